// Round 11
// baseline (655.789 us; speedup 1.0000x reference)
//
#include <hip/hip_runtime.h>
#include <hip/hip_bf16.h>

typedef unsigned short u16;
typedef unsigned int   u32;
typedef __attribute__((ext_vector_type(8))) short bf16x8;
typedef __attribute__((ext_vector_type(4))) float f32x4;
typedef __attribute__((ext_vector_type(4))) u16   u16x4;

constexpr int TT  = 2;
constexpr int NN  = 16384;
constexpr int EE  = 262144;

__device__ __forceinline__ u16 f2b(float f){
  u32 x = __float_as_uint(f);
  u32 r = (x + 0x7fffu + ((x >> 16) & 1u)) >> 16;
  return (u16)r;
}
__device__ __forceinline__ float b2f(u16 u){ return __uint_as_float(((u32)u) << 16); }
__device__ __forceinline__ u32 pack2bf(float a, float b){
  __hip_bfloat162 h = __float22bfloat162_rn(make_float2(a, b));
  union { __hip_bfloat162 h2; u32 u; } cv; cv.h2 = h; return cv.u;
}

// XOR-swizzled LDS addressing for stride-64 (u16) tiles: col c stored at
// c ^ ((row&7)*8). b128 fragment reads -> 2-way aliasing only (free, m136).
__device__ __forceinline__ int swz64(int row, int c){
  return (row << 6) + (c ^ ((row & 7) << 3));
}

// Async global->LDS, 16B per lane, wave-uniform LDS base (HW: base + lane*16).
__device__ __forceinline__ void gl_lds16(const u16* g, u16* l){
  __builtin_amdgcn_global_load_lds(
      (const __attribute__((address_space(1))) u32*)g,
      (__attribute__((address_space(3))) u32*)l, 16, 0, 0);
}

__device__ __forceinline__ float fast_tanh(float u){
  return 1.f - 2.f*__builtin_amdgcn_rcpf(1.f + __expf(2.f*u));
}
__device__ __forceinline__ float gelu_f(float x){
  float u = 0.7978845608028654f * (x + 0.044715f * x*x*x);
  return 0.5f * x * (1.f + fast_tanh(u));
}

// ---------------- CSR build ----------------
__global__ void csr_hist(const int* __restrict__ dst, int* __restrict__ cnt){
  int id = blockIdx.x*256 + threadIdx.x;
  int e = id >> 18;
  atomicAdd(&cnt[e*NN + dst[id]], 1);
}

__global__ void csr_scan(const int* __restrict__ cnt, int* __restrict__ offs){
  const int e = blockIdx.x, tid = threadIdx.x;
  const int CH = NN/256;
  const int* c = cnt + e*NN;
  int* of = offs + e*(NN+1);
  const int base = tid*CH;
  int s = 0;
  for(int i=0;i<CH;i++) s += c[base+i];
  __shared__ int sm[256];
  sm[tid] = s; __syncthreads();
  for(int o=1;o<256;o<<=1){
    int v = (tid>=o) ? sm[tid-o] : 0;
    __syncthreads();
    sm[tid] += v;
    __syncthreads();
  }
  int run = sm[tid] - s;
  for(int i=0;i<CH;i++){ of[base+i] = run; run += c[base+i]; }
  if(tid==255) of[NN] = run;
}

__global__ void csr_scatter(const int* __restrict__ dst, const int* __restrict__ src,
                            const int* __restrict__ offs, int* __restrict__ cur,
                            int* __restrict__ elist){
  int id = blockIdx.x*256 + threadIdx.x;
  int e = id >> 18;
  int d = dst[id];
  int pos = offs[e*(NN+1)+d] + atomicAdd(&cur[e*NN+d], 1);
  elist[e*EE + pos] = src[id];
}

// ---------------- transpose + bf16 convert (weights) ----------------
// ozstride: output offset per blockIdx.z (lets Q land inside the per-(l,t)
// [mergedKV | Q] blocks of qkvwt).
__global__ void tconv(const float* __restrict__ in, u16* __restrict__ out, int K, int Nc,
                      long ozstride){
  __shared__ float tile[32][33];
  const long ibase = (long)blockIdx.z * K * Nc;
  const long obase = (long)blockIdx.z * ozstride;
  const int k0 = blockIdx.x*32, n0 = blockIdx.y*32;
  const int tx = threadIdx.x, ty = threadIdx.y;
  for(int i=0;i<32;i+=8)
    tile[ty+i][tx] = in[ibase + (long)(k0+ty+i)*Nc + n0+tx];
  __syncthreads();
  for(int i=0;i<32;i+=8)
    out[obase + (long)(n0+ty+i)*K + k0+tx] = f2b(tile[tx][ty+i]);
}

// ---------------- fold head transforms into K/V weights ----------------
// R4: K_eff/V_eff columns pre-interleaved at 4-dim granularity into a merged
// 512-col weight block per (l,t): K dim c -> (c>>2)*8+(c&3), V dim c ->
// (c>>2)*8+4+(c&3).  One gemm z-slice produces a CONTIGUOUS half of the
// interleaved KV record -> 32B-dense stores.
// qkvwt per (l,t) block (196608 u16): [merged 512x256 | Q^T 256x256].
// qkvb per l (1536 f32): [t0 merged 512 | t1 merged 512 | t0 Q 256 | t1 Q 256].
__global__ void eff_w(const float* __restrict__ kw, const float* __restrict__ vw,
                      const float* __restrict__ kb, const float* __restrict__ vb,
                      const float* __restrict__ att, const float* __restrict__ val,
                      u16* __restrict__ qkvwt, float* __restrict__ qkvb){
  const int h = blockIdx.x, lt = blockIdx.y, kv = blockIdx.z;   // 8 x 4 x 2
  const int l = lt >> 1;
  const float* W = (kv ? vw : kw) + (long)lt*65536;
  const float* A = (kv ? val : att) + (long)lt*8192 + h*1024;
  const float* B = (kv ? vb : kb) + (long)lt*256 + h*32;
  __shared__ float As[32][33];
  for(int idx=threadIdx.x; idx<1024; idx+=256) As[idx>>5][idx&31] = A[idx];
  __syncthreads();
  const int r = threadIdx.x;
  float x[32];
  const float* wr = W + (long)r*256 + h*32;
  #pragma unroll
  for(int i=0;i<32;i++) x[i] = wr[i];
  u16* outb = qkvwt + (long)lt*196608;
  #pragma unroll 4
  for(int j=0;j<32;j++){
    float s = 0.f;
    #pragma unroll
    for(int i=0;i<32;i++) s = fmaf(x[i], As[i][j], s);
    const int c = h*32 + j;
    const int mc = ((c>>2)<<3) + kv*4 + (c&3);
    outb[(long)mc*256 + r] = f2b(s);
  }
  if (r < 32){
    float s = 0.f;
    #pragma unroll
    for(int i=0;i<32;i++) s = fmaf(B[i], As[i][r], s);
    const int c = h*32 + r;
    const int mc = ((c>>2)<<3) + kv*4 + (c&3);
    qkvb[l*1536 + (lt&1)*512 + mc] = s;
  }
}

__global__ void pack_qb(const float* __restrict__ qb, float* __restrict__ qkvb){
  int i = blockIdx.x*256 + threadIdx.x;   // 1024 = L*T*256
  int l = i >> 9, r = i & 511;
  qkvb[l*1536 + 1024 + r] = qb[l*512 + r];
}

// ---------------- Chebyshev fit of the posvect function bank ----------------
// R10 post-mortem: the fused DCT in posvect2 spilled on every phrasing (R9
// j-outer, R10 d-outer: VGPR 52, WRITE +24MB, 69us — allocator won't hold a
// 32-wide accumulator there). R11: the DCT is LINEAR, so it commutes with the
// h-reduction — DCT each h's activations FIRST (per-h coefficient partials
// via a cos recurrence; all multipliers uniform-scalar), with blockIdx.z now
// indexing 4 groups of 8 COEFFICIENTS j. The fw-weighted hot loop is
// cost-identical (acc[8]); the same atomicAdd reduction yields FINAL
// coefficients Cred[12][32j][256k]. posvect2 then just loads them.
__global__ void cheb_g(const float* __restrict__ ww, const float* __restrict__ wb,
                       const float* __restrict__ lw, const float* __restrict__ lb,
                       const float* __restrict__ sw, const float* __restrict__ sb,
                       const float* __restrict__ gw, const float* __restrict__ gb,
                       const float* __restrict__ fcw, float* __restrict__ Cred){
  const int p  = blockIdx.x;        // 8 chunks of 128 h
  const int by = blockIdx.y;        // t*6+m
  const int zg = blockIdx.z;        // 4 groups of 8 coefficients j
  const int s  = p >> 1;            // slab: 0 sin, 1 linear, 2 softplus, 3 sigmoid
  const int tid = threadIdx.x;
  __shared__ float as_[128][9];     // 8 coeff partials + pad
  if (tid < 128){
    // cos((d+0.5)*pi/32), d=0..31 (constexpr, static indices only)
    constexpr float C1[32] = {
       0.99879546f,  0.98917651f,  0.97003125f,  0.94154407f,
       0.90398929f,  0.85772861f,  0.80320753f,  0.74095113f,
       0.67155895f,  0.59569930f,  0.51410274f,  0.42755509f,
       0.33688985f,  0.24298018f,  0.14673047f,  0.04906767f,
      -0.04906767f, -0.14673047f, -0.24298018f, -0.33688985f,
      -0.42755509f, -0.51410274f, -0.59569930f, -0.67155895f,
      -0.74095113f, -0.80320753f, -0.85772861f, -0.90398929f,
      -0.94154407f, -0.97003125f, -0.98917651f, -0.99879546f };
    const int hl = (p & 1)*128 + tid;   // index within slab
    const float* W = (s==0 ? ww : s==1 ? lw : s==2 ? sw : gw) + by*256;
    const float* B = (s==0 ? wb : s==1 ? lb : s==2 ? sb : gb) + by*256;
    const float w = W[hl], b = B[hl];
    float act[32];
    #pragma unroll
    for (int d=0; d<32; d++){
      const float x = 0.5f*C1[d] + 0.5f;
      const float y = x*w + b;
      float a;
      if (s==0)      a = sinf(y);
      else if (s==1) a = y;
      else if (s==2) a = fmaxf(y,0.f) + log1pf(expf(-fabsf(y)));
      else           a = 1.f/(1.f + expf(-y));
      act[d] = a;
    }
    // per-h DCT of act[] for this block's 8 coefficients j = zg*8+jj.
    // cos(j*th_d) over d obeys t_{d+1} = 2cos(j*pi/32)*t_d - t_{d-1},
    // t_0 = t_{-1} = cos(j*pi/64). j uniform -> scalar multipliers.
    #pragma unroll
    for (int jj=0; jj<8; jj++){
      const int j = zg*8 + jj;
      const float mj = 2.f*cosf((float)j*(3.14159265358979323846f/32.f));
      float tp = cosf((float)j*(3.14159265358979323846f/64.f));
      float tc = tp;
      float a = 0.f;
      #pragma unroll
      for (int d=0; d<32; d++){
        a = fmaf(act[d], tc, a);
        const float tn = fmaf(mj, tc, -tp);
        tp = tc; tc = tn;
      }
      as_[tid][jj] = a;
    }
  }
  __syncthreads();
  const int k = tid;
  float acc[8];
  #pragma unroll
  for (int dd=0; dd<8; dd++) acc[dd] = 0.f;
  const float* fwp = fcw + ((long)by*1024 + p*128)*256 + k;
  for (int hh=0; hh<128; hh++){
    const float f = fwp[(long)hh*256];
    #pragma unroll
    for (int dd=0; dd<8; dd++) acc[dd] = fmaf(as_[hh][dd], f, acc[dd]);
  }
  float* gp = Cred + (long)by*8192 + (long)(zg*8)*256 + k;
  #pragma unroll
  for (int dd=0; dd<8; dd++) atomicAdd(&gp[dd*256], acc[dd]);
}

// ---------------- posvect: Chebyshev evaluation (K=32 GEMM) ----------------
// R7-verified chunk-local MFMA epilogue. Coefficients arrive PRE-COMPUTED in
// Cred (cheb_g does the DCT) — prologue is 32 coalesced loads + 16 packs,
// ~20 live regs (the in-kernel DCT spilled in R9/R10).
__global__ void __launch_bounds__(256,2)
posvect2(const float* __restrict__ scalars, const float* __restrict__ Cred,
         const float* __restrict__ fcb, u16* __restrict__ zb){
  __shared__ __align__(16) u16 lB[256*40];   // C^T, row stride 40 u16 (80B)
  __shared__ float xs[128];
  __shared__ float c0s[256];
  const int tid = threadIdx.x;
  const int by = blockIdx.y;                 // t*6+m
  const int t = by / 6, m = by % 6;
  const int m0 = blockIdx.x * 128;
  const int lane = tid & 63, wvi = tid >> 6;
  const int wc0 = wvi * 64;
  const int l16 = lane & 15, qd = lane >> 4;

  if (tid < 128) xs[tid] = scalars[((long)t*NN + m0 + tid)*6 + m];

  // ---- load coefficients: Cred[by][j][k=tid] ----
  {
    const float* gp = Cred + (long)by*8192 + tid;
    const float c0v = gp[0];
    c0s[tid] = c0v*(1.f/32.f) + fcb[by*256 + tid];
    u32 cw[16];
    cw[0] = pack2bf(0.f, gp[256]*(1.f/16.f));   // j=0 slot zeroed (in bias)
    #pragma unroll
    for (int j2=1;j2<16;j2++)
      cw[j2] = pack2bf(gp[(2*j2)*256]*(1.f/16.f), gp[(2*j2+1)*256]*(1.f/16.f));
    union { u32 w[4]; uint4 v; } cv4;
    #pragma unroll
    for (int q=0; q<4; q++){
      cv4.w[0]=cw[q*4]; cv4.w[1]=cw[q*4+1]; cv4.w[2]=cw[q*4+2]; cv4.w[3]=cw[q*4+3];
      *(uint4*)&lB[tid*40 + q*8] = cv4.v;    // tid*80B: 16B-aligned
    }
  }
  __syncthreads();

  // A-fragments: lane row = i*16 + l16, k-offset = qd*8
  bf16x8 af[8];
  #pragma unroll
  for (int i=0;i<8;i++){
    const float u = 2.f*xs[i*16 + l16] - 1.f;
    float t0 = 1.f, t1 = u;
    u32 pk[16];
    pk[0] = pack2bf(t0, t1);
    #pragma unroll
    for (int j2=1; j2<16; j2++){
      const float a = 2.f*u*t1 - t0;   // T_{2*j2}
      const float b = 2.f*u*a  - t1;   // T_{2*j2+1}
      pk[j2] = pack2bf(a, b);
      t0 = a; t1 = b;
    }
    u32 w[4];
    #pragma unroll
    for (int c=0;c<4;c++){
      const u32 v01 = (qd & 2) ? pk[8+c]  : pk[c];
      const u32 v23 = (qd & 2) ? pk[12+c] : pk[4+c];
      w[c] = (qd & 1) ? v23 : v01;
    }
    union { u32 u4[4]; bf16x8 v; } cv;
    cv.u4[0]=w[0]; cv.u4[1]=w[1]; cv.u4[2]=w[2]; cv.u4[3]=w[3];
    af[i] = cv.v;
  }

  bf16x8 bfr[4];
  #pragma unroll
  for (int jj=0;jj<4;jj++)
    bfr[jj] = *(const bf16x8*)&lB[(wc0 + jj*16 + l16)*40 + qd*8];

  // hoist the 4 bias values (col depends only on jj)
  float bvj[4];
  #pragma unroll
  for (int jj=0;jj<4;jj++) bvj[jj] = c0s[wc0 + jj*16 + l16];

  u16* st = (u16*)lB;                         // 32 x 264 u16 = 16.5 KB chunk
  u16* zout = zb + ((long)t*NN + m0)*1792 + (m+1)*256;
  #pragma unroll
  for (int c=0;c<4;c++){
    // chunk-local MFMA (rows c*32 .. c*32+31): 32 live accs only
    f32x4 acc2[2][4];
    #pragma unroll
    for (int ii=0;ii<2;ii++)
      #pragma unroll
      for (int jj=0;jj<4;jj++)
        acc2[ii][jj] = __builtin_amdgcn_mfma_f32_16x16x32_bf16(
            af[c*2+ii], bfr[jj], (f32x4){0.f,0.f,0.f,0.f}, 0,0,0);
    u32 pk2[2][4][2];
    #pragma unroll
    for (int ii=0;ii<2;ii++)
      #pragma unroll
      for (int jj=0;jj<4;jj++){
        pk2[ii][jj][0] = pack2bf(gelu_f(acc2[ii][jj][0] + bvj[jj]),
                                 gelu_f(acc2[ii][jj][1] + bvj[jj]));
        pk2[ii][jj][1] = pack2bf(gelu_f(acc2[ii][jj][2] + bvj[jj]),
                                 gelu_f(acc2[ii][jj][3] + bvj[jj]));
      }
    __syncthreads();                          // lB/prev-chunk reads done
    #pragma unroll
    for (int ii=0;ii<2;ii++){
      #pragma unroll
      for (int jj=0;jj<4;jj++){
        const int col = wc0 + jj*16 + l16;
        const int r0 = ii*16 + qd*4;
        st[(r0+0)*264 + col] = (u16)(pk2[ii][jj][0] & 0xffffu);
        st[(r0+1)*264 + col] = (u16)(pk2[ii][jj][0] >> 16);
        st[(r0+2)*264 + col] = (u16)(pk2[ii][jj][1] & 0xffffu);
        st[(r0+3)*264 + col] = (u16)(pk2[ii][jj][1] >> 16);
      }
    }
    __syncthreads();
    #pragma unroll
    for (int it=0; it<4; it++){
      const int f = it*256 + tid;             // 1024 = 32 rows x 32 segs
      const int rowl = f >> 5, seg = f & 31;
      const uint4 v = *(const uint4*)&st[rowl*264 + seg*8];
      *(uint4*)&zout[(long)(c*32 + rowl)*1792 + seg*8] = v;
    }
  }
}

// ---------------- generic bf16-MFMA GEMM (swizzled LDS + async staging) ---------
// EPI: 0 = fp32 +bias; 1 = gelu->bf16; 4 = tanh dot w2 row-sum; 5 = residual mix + LayerNorm
// ASRC: 0 = fp32 A (VGPR cvt path); 1 = bf16 A (async global_load_lds).
// ZQKV: blockIdx.z = {KVlo, KVhi, Q}: z<2 -> contiguous half of the
// interleaved KV record (merged pre-interleaved weights), z=2 -> Q bf16.
// launch_bounds(256,2): (256,3+) spills the MFMA accumulators. Do not raise.
template<int BM,int BN,int BK,int WM,int WN,int ASRC,int EPI,int ZQKV>
__global__ void __launch_bounds__(256,2)
gemm_k(const void* __restrict__ Av, const u16* __restrict__ Bt,
       const float* __restrict__ bias, void* Cv,
       int K, int lda, int ldc,
       long strideA, long strideB, long strideBias, long strideC,
       const float* resid, const float* __restrict__ resgate,
       const int* __restrict__ selp, u16* __restrict__ kvout,
       const float* __restrict__ lng, const float* __restrict__ lnb)
{
  static_assert(BK == 64, "swizzle assumes BK=64");
  constexpr int WTM = BM/WM, WTN = BN/WN;
  constexpr int RM = WTM/16, RN = WTN/16;
  __shared__ __align__(16) u16 lA[BM*64];
  __shared__ __align__(16) u16 lB[BN*64];

  const int tid = threadIdx.x;
  const int by  = blockIdx.y;
  const int m0  = blockIdx.x * BM;
  const int lane = tid & 63, wvi = tid >> 6;
  const int wr = wvi / WN, wc = wvi % WN;
  const int wr0 = wr * WTM, wc0 = wc * WTN;
  const int l16 = lane & 15, qd = lane >> 4;
  // per-lane source-column permutation implementing the XOR swizzle (see gl_lds16)
  const int csrc = (((lane & 7) ^ (lane >> 3)) << 3);

  int zq = 0;
  if constexpr (ZQKV) zq = blockIdx.z;

  long aoff = (long)by * strideA;
  if (selp) aoff += (long)selp[0] * strideA;
  const float* A32 = (const float*)Av;
  const u16*   A16 = (const u16*)Av;
  const u16*   Bp  = Bt + (long)by * strideB + (long)zq * 65536;

  f32x4 acc[RM][RN];
  #pragma unroll
  for(int i=0;i<RM;i++)
    #pragma unroll
    for(int j=0;j<RN;j++) acc[i][j] = (f32x4){0.f,0.f,0.f,0.f};

  for(int k0=0;k0<K;k0+=BK){
    if constexpr (ASRC == 0){
      for(int idx=tid; idx < BM*16; idx += 256){
        int r = idx >> 4, c = (idx & 15)*4;
        const float4 v = *(const float4*)(A32 + aoff + (long)(m0+r)*lda + k0 + c);
        uint2 o2; o2.x = pack2bf(v.x, v.y); o2.y = pack2bf(v.z, v.w);
        *(uint2*)&lA[swz64(r, c)] = o2;
      }
    } else {
      #pragma unroll
      for(int ch = wvi; ch < BM/8; ch += 4){
        const int r = ch*8 + (lane>>3);
        gl_lds16(A16 + aoff + (long)(m0+r)*lda + k0 + csrc, &lA[ch*512]);
      }
    }
    #pragma unroll
    for(int ch = wvi; ch < BN/8; ch += 4){
      const int n = ch*8 + (lane>>3);
      gl_lds16(Bp + (long)n*K + k0 + csrc, &lB[ch*512]);
    }
    __syncthreads();
    #pragma unroll
    for(int ks=0; ks<BK; ks+=32){
      bf16x8 af[RM], bfr[RN];
      #pragma unroll
      for(int i=0;i<RM;i++) af[i]  = *(const bf16x8*)&lA[swz64(wr0 + i*16 + l16, ks + qd*8)];
      #pragma unroll
      for(int j=0;j<RN;j++) bfr[j] = *(const bf16x8*)&lB[swz64(wc0 + j*16 + l16, ks + qd*8)];
      #pragma unroll
      for(int i=0;i<RM;i++)
        #pragma unroll
        for(int j=0;j<RN;j++)
          acc[i][j] = __builtin_amdgcn_mfma_f32_16x16x32_bf16(af[i], bfr[j], acc[i][j], 0,0,0);
    }
    __syncthreads();
  }

  if constexpr (EPI == 4){
    float* rsum = (float*)lA;   // alias dead A-tile (post-barrier safe)
    #pragma unroll
    for(int i=0;i<RM;i++){
      #pragma unroll
      for(int r=0;r<4;r++){
        float part = 0.f;
        #pragma unroll
        for(int jj=0;jj<RN;jj++){
          const int col = wc0 + jj*16 + l16;
          const float v = fast_tanh(acc[i][jj][r] + bias[col]);
          part += v * resid[col];
        }
        part += __shfl_xor(part,1); part += __shfl_xor(part,2);
        part += __shfl_xor(part,4); part += __shfl_xor(part,8);
        if (l16 == 0) rsum[wc*BM + wr0 + i*16 + qd*4 + r] = part;
      }
    }
    __syncthreads();
    if (tid < BM){
      float s = 0.f;
      #pragma unroll
      for(int w=0;w<WN;w++) s += rsum[w*BM + tid];
      ((float*)Cv)[m0 + tid] = s;
    }
    return;
  } else if constexpr (EPI == 5){
    // residual mix -> LayerNorm fused; Cv == resid buffer (in-place per-row)
    float* red1 = (float*)lA;            // WN*BM
    float* red2 = red1 + WN*BM;          // WN*BM
    float* muv  = red2 + WN*BM;          // BM*2
    const float alpha = 1.f/(1.f + __expf(-resgate[by]));
    #pragma unroll
    for(int i=0;i<RM;i++){
      #pragma unroll
      for(int r=0;r<4;r++){
        const int rloc = wr0 + i*16 + qd*4 + r;
        const int row = m0 + rloc;
        float s1 = 0.f, s2 = 0.f;
        #pragma unroll
        for(int j=0;j<RN;j++){
          const int col = wc0 + j*16 + l16;
          float v = acc[i][j][r] + bias[(long)by*strideBias + col];
          const float hv = resid[(long)by*strideC + (long)row*ldc + col];
          v = v*alpha + hv*(1.f - alpha);
          acc[i][j][r] = v;
          s1 += v; s2 += v*v;
        }
        s1 += __shfl_xor(s1,1); s1 += __shfl_xor(s1,2); s1 += __shfl_xor(s1,4); s1 += __shfl_xor(s1,8);
        s2 += __shfl_xor(s2,1); s2 += __shfl_xor(s2,2); s2 += __shfl_xor(s2,4); s2 += __shfl_xor(s2,8);
        if (l16 == 0){ red1[wc*BM + rloc] = s1; red2[wc*BM + rloc] = s2; }
      }
    }
    __syncthreads();
    if (tid < BM){
      float s1 = 0.f, s2 = 0.f;
      #pragma unroll
      for(int w=0;w<WN;w++){ s1 += red1[w*BM + tid]; s2 += red2[w*BM + tid]; }
      const float mu = s1*(1.f/256.f);
      const float var = s2*(1.f/256.f) - mu*mu;
      muv[tid*2]   = mu;
      muv[tid*2+1] = rsqrtf(fmaxf(var, 0.f) + 1e-5f);
    }
    __syncthreads();
    #pragma unroll
    for(int i=0;i<RM;i++){
      #pragma unroll
      for(int r=0;r<4;r++){
        const int rloc = wr0 + i*16 + qd*4 + r;
        const int row = m0 + rloc;
        const float mu = muv[rloc*2], rs = muv[rloc*2+1];
        #pragma unroll
        for(int j=0;j<RN;j++){
          const int col = wc0 + j*16 + l16;
          const float o = (acc[i][j][r]-mu)*rs*lng[by*256+col] + lnb[by*256+col];
          ((float*)Cv)[(long)by*strideC + (long)row*ldc + col] = o;
        }
      }
    }
    return;
  } else {
    #pragma unroll
    for(int i=0;i<RM;i++){
      #pragma unroll
      for(int j=0;j<RN;j++){
        const int col = wc0 + j*16 + l16;
        float bv;
        if constexpr (ZQKV)
          bv = bias[(zq==2) ? (1024 + (long)by*256 + col) : ((long)by*512 + zq*256 + col)];
        else
          bv = bias[(long)by*strideBias + col];
        #pragma unroll
        for(int r=0;r<4;r++){
          const int row = m0 + wr0 + i*16 + qd*4 + r;
          float v = acc[i][j][r] + bv;
          if constexpr (ZQKV){
            if (zq == 2)
              ((u16*)Cv)[(long)by*strideC + (long)row*ldc + col] = f2b(v);   // Q bf16
            else
              // contiguous half of the interleaved KV record (32B-dense)
              kvout[((long)by*NN + row)*512 + zq*256 + col] = f2b(v);
          } else {
            const long cidx = (long)by*strideC + (long)row*ldc + col;
            if constexpr (EPI == 0) ((float*)Cv)[cidx] = v;
            else ((u16*)Cv)[cidx] = f2b(gelu_f(v));
          }
        }
      }
    }
  }
}

// ---------------- IMA combine ----------------
__global__ void ima_combine(const u16* __restrict__ zb, const float* __restrict__ wbuf,
                            float* __restrict__ H){
  const int row = blockIdx.x*4 + (threadIdx.x>>6);
  const int lane = threadIdx.x & 63;
  const float* w7 = wbuf + (long)row*7;
  float w[7]; float mx = -1e30f;
  #pragma unroll
  for(int m=0;m<7;m++){ w[m] = w7[m]; mx = fmaxf(mx, w[m]); }
  float sum = 0.f;
  #pragma unroll
  for(int m=0;m<7;m++){ w[m] = __expf(w[m]-mx); sum += w[m]; }
  const float inv = __builtin_amdgcn_rcpf(sum);
  float4 acc = {0,0,0,0};
  #pragma unroll
  for(int m=0;m<7;m++){
    const u16x4 z4 = *(const u16x4*)&zb[((long)row*7 + m)*256 + lane*4];
    const float p = w[m]*inv;
    acc.x += p*b2f(z4.x); acc.y += p*b2f(z4.y); acc.z += p*b2f(z4.z); acc.w += p*b2f(z4.w);
  }
  *(float4*)&H[(long)row*256 + lane*4] = acc;
}

// ---------------- attention aggregation: interleaved-KV gather ----------------
// KV record = 64 chunks of 16B; chunk l = {K[4l..4l+3], V[4l..4l+3]}.
// Lane l owns 4 K dims AND 4 V dims of head (l>>3); 8 lanes per head.
// R2/R4-verified at 66.2us: 256 threads, 4 dests/block. (R5's 64-thread
// 1-dest variant hit the 16-workgroup/CU cap -> reverted.)
__global__ void attn_agg(const u16* __restrict__ Q16, const u16* __restrict__ KV,
                         u16* __restrict__ AGG,
                         const int* __restrict__ offs, const int* __restrict__ elist,
                         const float* __restrict__ canon){
  const int e = blockIdx.y, dt = 1 - e;
  const int d = blockIdx.x*4 + (threadIdx.x>>6);
  const int lane = threadIdx.x & 63;
  const float scale = canon[e*8 + (lane>>3)] * 0.17677669529663687f;

  // Q dims lane*4..+3 (8B per lane, 512B per dest row)
  const uint2 qv = *(const uint2*)&Q16[((long)dt*NN + d)*256 + lane*4];
  const float q0 = b2f((u16)(qv.x&0xffff)), q1 = b2f((u16)(qv.x>>16));
  const float q2 = b2f((u16)(qv.y&0xffff)), q3 = b2f((u16)(qv.y>>16));

  const int p0 = offs[e*(NN+1) + d], p1 = offs[e*(NN+1) + d + 1];
  const int* el = elist + (long)e*EE;
  const u16* KVb = KV + (long)e*NN*512;

  float a0=0.f, a1=0.f, a2=0.f, a3=0.f;
  float den = 0.f;

  auto process = [&](const uint4 kv){
    float dp = q0*b2f((u16)(kv.x&0xffff)) + q1*b2f((u16)(kv.x>>16))
             + q2*b2f((u16)(kv.y&0xffff)) + q3*b2f((u16)(kv.y>>16));
    dp += __shfl_xor(dp,1); dp += __shfl_xor(dp,2); dp += __shfl_xor(dp,4);
    const float w = __expf(dp*scale);   // identical across the 8-lane head group
    den += w;
    a0 = fmaf(w, b2f((u16)(kv.z&0xffff)), a0);
    a1 = fmaf(w, b2f((u16)(kv.z>>16)),    a1);
    a2 = fmaf(w, b2f((u16)(kv.w&0xffff)), a2);
    a3 = fmaf(w, b2f((u16)(kv.w>>16)),    a3);
  };

  int p = p0;
  for(; p+8 <= p1; p += 8){
    uint4 kv[8];
    #pragma unroll
    for(int u=0;u<8;u++) kv[u] = *(const uint4*)&KVb[(long)el[p+u]*512 + lane*8];
    #pragma unroll
    for(int u=0;u<8;u++) process(kv[u]);
  }
  for(; p+2 <= p1; p += 2){
    const uint4 a = *(const uint4*)&KVb[(long)el[p]*512 + lane*8];
    const uint4 b = *(const uint4*)&KVb[(long)el[p+1]*512 + lane*8];
    process(a); process(b);
  }
  if (p < p1){
    const uint4 a = *(const uint4*)&KVb[(long)el[p]*512 + lane*8];
    process(a);
  }

  uint2 o = {0,0};
  if (p1 > p0){
    const float r = 1.f/den;
    o.x = pack2bf(a0*r, a1*r);
    o.y = pack2bf(a2*r, a3*r);
  }
  *(uint2*)&AGG[((long)dt*NN + d)*256 + lane*4] = o;
}

// ---------------- host ----------------
extern "C" void kernel_launch(void* const* d_in, const int* in_sizes, int n_in,
                              void* d_out, int out_size, void* d_ws, size_t ws_size,
                              hipStream_t stream) {
  const float* node_ft = (const float*)d_in[0];
  const float* scalars = (const float*)d_in[1];
  const int*   src_idx = (const int*)d_in[2];
  const int*   dst_idx = (const int*)d_in[3];
  const float* proj_w  = (const float*)d_in[4];
  const float* proj_b  = (const float*)d_in[5];
  const float* pv_ww   = (const float*)d_in[6];
  const float* pv_wb   = (const float*)d_in[7];
  const float* pv_lw   = (const float*)d_in[8];
  const float* pv_lb   = (const float*)d_in[9];
  const float* pv_sw   = (const float*)d_in[10];
  const float* pv_sb   = (const float*)d_in[11];
  const float* pv_gw   = (const float*)d_in[12];
  const float* pv_gb   = (const float*)d_in[13];
  const float* pv_fcw  = (const float*)d_in[14];
  const float* pv_fcb  = (const float*)d_in[15];
  const float* ima_w1  = (const float*)d_in[16];
  const float* ima_b1  = (const float*)d_in[17];
  const float* ima_w2  = (const float*)d_in[18];
  const float* lyr_k_w = (const float*)d_in[19];
  const float* lyr_q_w = (const float*)d_in[20];
  const float* lyr_v_w = (const float*)d_in[21];
  const float* lyr_fc_w= (const float*)d_in[22];
  const float* lyr_k_b = (const float*)d_in[23];
  const float* lyr_q_b = (const float*)d_in[24];
  const float* lyr_v_b = (const float*)d_in[25];
  const float* lyr_fc_b= (const float*)d_in[26];
  const float* lyr_att_w=(const float*)d_in[27];
  const float* lyr_val_w=(const float*)d_in[28];
  const float* lyr_canon=(const float*)d_in[29];
  const float* lyr_res = (const float*)d_in[30];
  const float* lyr_ln_g= (const float*)d_in[31];
  const float* lyr_ln_b= (const float*)d_in[32];
  const float* out_w   = (const float*)d_in[33];
  const float* out_b   = (const float*)d_in[34];
  const int*   sel     = (const int*)d_in[35];
  float* outp = (float*)d_out;

  char* ws = (char*)d_ws;
  size_t o = 0;
  auto alloc = [&](size_t bytes)->char*{ char* p = ws + o; o = (o + bytes + 255) & ~(size_t)255; return p; };

  int*   cnt    = (int*)  alloc(2*NN*4);
  int*   cur    = (int*)  alloc(2*NN*4);
  int*   offs   = (int*)  alloc(2*(NN+1)*4);
  int*   elist  = (int*)  alloc(2*EE*4);
  u16*   projwt = (u16*)  alloc((size_t)TT*128*256*2);
  u16*   imaw1t = (u16*)  alloc((size_t)256*128*2);
  u16*   qkvwt  = (u16*)  alloc((size_t)4*196608*2);   // per (l,t): [mergedKV 512x256 | Q 256x256]
  u16*   fcwt   = (u16*)  alloc((size_t)4*256*256*2);
  u16*   outwt  = (u16*)  alloc((size_t)64*256*2);
  float* hbuf   = (float*)alloc((size_t)TT*NN*256*4);
  float* wbuf   = (float*)alloc((size_t)TT*NN*7*4);
  float* Cred   = (float*)alloc((size_t)12*32*256*4);     // cheb coefficients (fp32)
  float* qkvb   = (float*)alloc((size_t)TT*3*2*256*4);    // per l: [t0 m512|t1 m512|t0 Q256|t1 Q256]
  char*  arena  = alloc((size_t)176160768);
  if (o > ws_size) return;

  u16*   zbuf  = (u16*)arena;                         // (T,N,7,256) bf16, phase A
  u16*   Qb16  = (u16*)arena;                         // phase B (zbuf dead after ima_combine)
  u16*   KVb   = (u16*)(arena + 16777216);            // (T,N,512) bf16 interleaved K|V
  u16*   AGG16 = (u16*)(arena + 50331648);            // (T,N,256) bf16

  // ---- CSR build ----
  hipMemsetAsync(cnt, 0, 2*NN*4, stream);
  hipMemsetAsync(cur, 0, 2*NN*4, stream);
  hipMemsetAsync(Cred, 0, (size_t)12*32*256*4, stream);
  csr_hist   <<<2*EE/256, 256, 0, stream>>>(dst_idx, cnt);
  csr_scan   <<<2, 256, 0, stream>>>(cnt, offs);
  csr_scatter<<<2*EE/256, 256, 0, stream>>>(dst_idx, src_idx, offs, cur, elist);

  // ---- weights prep ----
  tconv<<<dim3( 4,8, 2), dim3(32,8), 0, stream>>>(proj_w,   projwt, 128, 256, 32768L);
  tconv<<<dim3( 8,4, 1), dim3(32,8), 0, stream>>>(ima_w1,   imaw1t, 256, 128, 32768L);
  tconv<<<dim3( 8,8, 4), dim3(32,8), 0, stream>>>(lyr_q_w,  qkvwt + 131072, 256, 256, 196608L);
  tconv<<<dim3( 8,8, 4), dim3(32,8), 0, stream>>>(lyr_fc_w, fcwt,   256, 256, 65536L);
  tconv<<<dim3( 8,2, 1), dim3(32,8), 0, stream>>>(out_w,    outwt,  256, 64, 16384L);
  eff_w<<<dim3(8,4,2), 256, 0, stream>>>(lyr_k_w, lyr_v_w, lyr_k_b, lyr_v_b,
                                         lyr_att_w, lyr_val_w, qkvwt, qkvb);
  pack_qb<<<4, 256, 0, stream>>>(lyr_q_b, qkvb);

  // ---- Chebyshev fit of posvect (per-h DCT inside cheb_g) ----
  cheb_g<<<dim3(8,12,4), 256, 0, stream>>>(pv_ww, pv_wb, pv_lw, pv_lb,
                                           pv_sw, pv_sb, pv_gw, pv_gb, pv_fcw, Cred);

  // ---- h0 = gelu(node_ft @ proj_w + b) -> zbuf slot 0 ----
  gemm_k<64,256,64,1,4,0,1,0><<<dim3(256,TT), 256, 0, stream>>>(
      node_ft, projwt, proj_b, zbuf, 128, 128, 1792,
      (long)NN*128, 32768L, 256L, (long)NN*1792, nullptr, nullptr, nullptr, nullptr,
      nullptr, nullptr);

  // ---- posvect -> zbuf slots 1..6 (Chebyshev evaluation, K=32) ----
  posvect2<<<dim3(128,12), 256, 0, stream>>>(scalars, Cred, pv_fcb, zbuf);

  // ---- IMA gate fused epilogue, then softmax-combine ----
  gemm_k<64,128,64,2,2,1,4,0><<<dim3(3584,1), 256, 0, stream>>>(
      zbuf, imaw1t, ima_b1, wbuf, 256, 256, 0,
      0L, 0L, 0L, 0L, ima_w2, nullptr, nullptr, nullptr, nullptr, nullptr);
  ima_combine<<<TT*NN/4, 256, 0, stream>>>(zbuf, wbuf, hbuf);

  // ---- layers ----
  for (int l = 0; l < 2; ++l){
    // merged K/Q/V: z=0/1 -> contiguous KV record halves, z=2 -> Q
    gemm_k<64,256,64,1,4,0,0,1><<<dim3(256,TT,3), 256, 0, stream>>>(
        hbuf, qkvwt + (size_t)l*393216, qkvb + (size_t)l*1536, Qb16, 256, 256, 256,
        (long)NN*256, 196608L, 0L, (long)NN*256, nullptr, nullptr, nullptr, KVb,
        nullptr, nullptr);

    attn_agg<<<dim3(NN/4, 2), 256, 0, stream>>>(Qb16, KVb, AGG16, offs, elist,
                                                lyr_canon + l*2*8);

    // fc + residual mix + LayerNorm fused, in-place on hbuf
    gemm_k<64,256,64,1,4,1,5,0><<<dim3(256,TT), 256, 0, stream>>>(
        AGG16, fcwt + (size_t)l*2*65536, lyr_fc_b + l*2*256, hbuf, 256, 256, 256,
        (long)NN*256, 65536L, 256L, (long)NN*256, hbuf, lyr_res + l*2, nullptr, nullptr,
        lyr_ln_g + l*2*256, lyr_ln_b + l*2*256);
  }

  // ---- out = h[sel] @ out_w + out_b ----
  gemm_k<256,64,64,4,1,0,0,0><<<dim3(64,1), 256, 0, stream>>>(
      hbuf, outwt, out_b, outp, 256, 256, 64,
      (long)NN*256, 0L, 0L, 0L, nullptr, nullptr, sel, nullptr, nullptr, nullptr);

  (void)in_sizes; (void)n_in; (void)out_size;
}

// Round 13
// 632.026 us; speedup vs baseline: 1.0376x; 1.0376x over previous
//
#include <hip/hip_runtime.h>
#include <hip/hip_bf16.h>

typedef unsigned short u16;
typedef unsigned int   u32;
typedef __attribute__((ext_vector_type(8))) short bf16x8;
typedef __attribute__((ext_vector_type(4))) float f32x4;
typedef __attribute__((ext_vector_type(4))) u16   u16x4;

constexpr int TT  = 2;
constexpr int NN  = 16384;
constexpr int EE  = 262144;

__device__ __forceinline__ u16 f2b(float f){
  u32 x = __float_as_uint(f);
  u32 r = (x + 0x7fffu + ((x >> 16) & 1u)) >> 16;
  return (u16)r;
}
__device__ __forceinline__ float b2f(u16 u){ return __uint_as_float(((u32)u) << 16); }
__device__ __forceinline__ u32 pack2bf(float a, float b){
  __hip_bfloat162 h = __float22bfloat162_rn(make_float2(a, b));
  union { __hip_bfloat162 h2; u32 u; } cv; cv.h2 = h; return cv.u;
}

// XOR-swizzled LDS addressing for stride-64 (u16) tiles: col c stored at
// c ^ ((row&7)*8). b128 fragment reads -> 2-way aliasing only (free, m136).
__device__ __forceinline__ int swz64(int row, int c){
  return (row << 6) + (c ^ ((row & 7) << 3));
}

// Async global->LDS, 16B per lane, wave-uniform LDS base (HW: base + lane*16).
__device__ __forceinline__ void gl_lds16(const u16* g, u16* l){
  __builtin_amdgcn_global_load_lds(
      (const __attribute__((address_space(1))) u32*)g,
      (__attribute__((address_space(3))) u32*)l, 16, 0, 0);
}

__device__ __forceinline__ float fast_tanh(float u){
  return 1.f - 2.f*__builtin_amdgcn_rcpf(1.f + __expf(2.f*u));
}
__device__ __forceinline__ float gelu_f(float x){
  float u = 0.7978845608028654f * (x + 0.044715f * x*x*x);
  return 0.5f * x * (1.f + fast_tanh(u));
}

// ---------------- CSR build ----------------
__global__ void csr_hist(const int* __restrict__ dst, int* __restrict__ cnt){
  int id = blockIdx.x*256 + threadIdx.x;
  int e = id >> 18;
  atomicAdd(&cnt[e*NN + dst[id]], 1);
}

__global__ void csr_scan(const int* __restrict__ cnt, int* __restrict__ offs){
  const int e = blockIdx.x, tid = threadIdx.x;
  const int CH = NN/256;
  const int* c = cnt + e*NN;
  int* of = offs + e*(NN+1);
  const int base = tid*CH;
  int s = 0;
  for(int i=0;i<CH;i++) s += c[base+i];
  __shared__ int sm[256];
  sm[tid] = s; __syncthreads();
  for(int o=1;o<256;o<<=1){
    int v = (tid>=o) ? sm[tid-o] : 0;
    __syncthreads();
    sm[tid] += v;
    __syncthreads();
  }
  int run = sm[tid] - s;
  for(int i=0;i<CH;i++){ of[base+i] = run; run += c[base+i]; }
  if(tid==255) of[NN] = run;
}

__global__ void csr_scatter(const int* __restrict__ dst, const int* __restrict__ src,
                            const int* __restrict__ offs, int* __restrict__ cur,
                            int* __restrict__ elist){
  int id = blockIdx.x*256 + threadIdx.x;
  int e = id >> 18;
  int d = dst[id];
  int pos = offs[e*(NN+1)+d] + atomicAdd(&cur[e*NN+d], 1);
  elist[e*EE + pos] = src[id];
}

// ---------------- transpose + bf16 convert (weights) ----------------
// ozstride: output offset per blockIdx.z (lets Q land inside the per-(l,t)
// [mergedKV | Q] blocks of qkvwt).
__global__ void tconv(const float* __restrict__ in, u16* __restrict__ out, int K, int Nc,
                      long ozstride){
  __shared__ float tile[32][33];
  const long ibase = (long)blockIdx.z * K * Nc;
  const long obase = (long)blockIdx.z * ozstride;
  const int k0 = blockIdx.x*32, n0 = blockIdx.y*32;
  const int tx = threadIdx.x, ty = threadIdx.y;
  for(int i=0;i<32;i+=8)
    tile[ty+i][tx] = in[ibase + (long)(k0+ty+i)*Nc + n0+tx];
  __syncthreads();
  for(int i=0;i<32;i+=8)
    out[obase + (long)(n0+ty+i)*K + k0+tx] = f2b(tile[tx][ty+i]);
}

// ---------------- fold head transforms into K/V weights ----------------
// R4: K_eff/V_eff columns pre-interleaved at 4-dim granularity into a merged
// 512-col weight block per (l,t): K dim c -> (c>>2)*8+(c&3), V dim c ->
// (c>>2)*8+4+(c&3).  One gemm z-slice produces a CONTIGUOUS half of the
// interleaved KV record -> 32B-dense stores.
// qkvwt per (l,t) block (196608 u16): [merged 512x256 | Q^T 256x256].
// qkvb per l (1536 f32): [t0 merged 512 | t1 merged 512 | t0 Q 256 | t1 Q 256].
__global__ void eff_w(const float* __restrict__ kw, const float* __restrict__ vw,
                      const float* __restrict__ kb, const float* __restrict__ vb,
                      const float* __restrict__ att, const float* __restrict__ val,
                      u16* __restrict__ qkvwt, float* __restrict__ qkvb){
  const int h = blockIdx.x, lt = blockIdx.y, kv = blockIdx.z;   // 8 x 4 x 2
  const int l = lt >> 1;
  const float* W = (kv ? vw : kw) + (long)lt*65536;
  const float* A = (kv ? val : att) + (long)lt*8192 + h*1024;
  const float* B = (kv ? vb : kb) + (long)lt*256 + h*32;
  __shared__ float As[32][33];
  for(int idx=threadIdx.x; idx<1024; idx+=256) As[idx>>5][idx&31] = A[idx];
  __syncthreads();
  const int r = threadIdx.x;
  float x[32];
  const float* wr = W + (long)r*256 + h*32;
  #pragma unroll
  for(int i=0;i<32;i++) x[i] = wr[i];
  u16* outb = qkvwt + (long)lt*196608;
  #pragma unroll 4
  for(int j=0;j<32;j++){
    float s = 0.f;
    #pragma unroll
    for(int i=0;i<32;i++) s = fmaf(x[i], As[i][j], s);
    const int c = h*32 + j;
    const int mc = ((c>>2)<<3) + kv*4 + (c&3);
    outb[(long)mc*256 + r] = f2b(s);
  }
  if (r < 32){
    float s = 0.f;
    #pragma unroll
    for(int i=0;i<32;i++) s = fmaf(B[i], As[i][r], s);
    const int c = h*32 + r;
    const int mc = ((c>>2)<<3) + kv*4 + (c&3);
    qkvb[l*1536 + (lt&1)*512 + mc] = s;
  }
}

__global__ void pack_qb(const float* __restrict__ qb, float* __restrict__ qkvb){
  int i = blockIdx.x*256 + threadIdx.x;   // 1024 = L*T*256
  int l = i >> 9, r = i & 511;
  qkvb[l*1536 + 1024 + r] = qb[l*512 + r];
}

// ---------------- Chebyshev fit of the posvect function bank ----------------
// R11-verified: the DCT is LINEAR, so it commutes with the h-reduction —
// each h DCTs its own activations (scalar cos recurrence, uniform
// multipliers); blockIdx.z indexes 4 groups of 8 coefficients j. atomicAdd
// reduction yields FINAL coefficients Cred[12][32j][256k].
__global__ void cheb_g(const float* __restrict__ ww, const float* __restrict__ wb,
                       const float* __restrict__ lw, const float* __restrict__ lb,
                       const float* __restrict__ sw, const float* __restrict__ sb,
                       const float* __restrict__ gw, const float* __restrict__ gb,
                       const float* __restrict__ fcw, float* __restrict__ Cred){
  const int p  = blockIdx.x;        // 8 chunks of 128 h
  const int by = blockIdx.y;        // t*6+m
  const int zg = blockIdx.z;        // 4 groups of 8 coefficients j
  const int s  = p >> 1;            // slab: 0 sin, 1 linear, 2 softplus, 3 sigmoid
  const int tid = threadIdx.x;
  __shared__ float as_[128][9];     // 8 coeff partials + pad
  if (tid < 128){
    constexpr float C1[32] = {
       0.99879546f,  0.98917651f,  0.97003125f,  0.94154407f,
       0.90398929f,  0.85772861f,  0.80320753f,  0.74095113f,
       0.67155895f,  0.59569930f,  0.51410274f,  0.42755509f,
       0.33688985f,  0.24298018f,  0.14673047f,  0.04906767f,
      -0.04906767f, -0.14673047f, -0.24298018f, -0.33688985f,
      -0.42755509f, -0.51410274f, -0.59569930f, -0.67155895f,
      -0.74095113f, -0.80320753f, -0.85772861f, -0.90398929f,
      -0.94154407f, -0.97003125f, -0.98917651f, -0.99879546f };
    const int hl = (p & 1)*128 + tid;   // index within slab
    const float* W = (s==0 ? ww : s==1 ? lw : s==2 ? sw : gw) + by*256;
    const float* B = (s==0 ? wb : s==1 ? lb : s==2 ? sb : gb) + by*256;
    const float w = W[hl], b = B[hl];
    float act[32];
    #pragma unroll
    for (int d=0; d<32; d++){
      const float x = 0.5f*C1[d] + 0.5f;
      const float y = x*w + b;
      float a;
      if (s==0)      a = sinf(y);
      else if (s==1) a = y;
      else if (s==2) a = fmaxf(y,0.f) + log1pf(expf(-fabsf(y)));
      else           a = 1.f/(1.f + expf(-y));
      act[d] = a;
    }
    // per-h DCT: cos(j*th_d) obeys t_{d+1} = 2cos(j*pi/32)*t_d - t_{d-1},
    // t_0 = t_{-1} = cos(j*pi/64). j uniform -> scalar multipliers.
    #pragma unroll
    for (int jj=0; jj<8; jj++){
      const int j = zg*8 + jj;
      const float mj = 2.f*cosf((float)j*(3.14159265358979323846f/32.f));
      float tp = cosf((float)j*(3.14159265358979323846f/64.f));
      float tc = tp;
      float a = 0.f;
      #pragma unroll
      for (int d=0; d<32; d++){
        a = fmaf(act[d], tc, a);
        const float tn = fmaf(mj, tc, -tp);
        tp = tc; tc = tn;
      }
      as_[tid][jj] = a;
    }
  }
  __syncthreads();
  const int k = tid;
  float acc[8];
  #pragma unroll
  for (int dd=0; dd<8; dd++) acc[dd] = 0.f;
  const float* fwp = fcw + ((long)by*1024 + p*128)*256 + k;
  for (int hh=0; hh<128; hh++){
    const float f = fwp[(long)hh*256];
    #pragma unroll
    for (int dd=0; dd<8; dd++) acc[dd] = fmaf(as_[hh][dd], f, acc[dd]);
  }
  float* gp = Cred + (long)by*8192 + (long)(zg*8)*256 + k;
  #pragma unroll
  for (int dd=0; dd<8; dd++) atomicAdd(&gp[dd*256], acc[dd]);
}

// ---------------- posvect: Chebyshev evaluation (K=32 GEMM) ----------------
// R7-verified chunk-local MFMA epilogue. Coefficients pre-computed in Cred.
__global__ void __launch_bounds__(256,2)
posvect2(const float* __restrict__ scalars, const float* __restrict__ Cred,
         const float* __restrict__ fcb, u16* __restrict__ zb){
  __shared__ __align__(16) u16 lB[256*40];   // C^T, row stride 40 u16 (80B)
  __shared__ float xs[128];
  __shared__ float c0s[256];
  const int tid = threadIdx.x;
  const int by = blockIdx.y;                 // t*6+m
  const int t = by / 6, m = by % 6;
  const int m0 = blockIdx.x * 128;
  const int lane = tid & 63, wvi = tid >> 6;
  const int wc0 = wvi * 64;
  const int l16 = lane & 15, qd = lane >> 4;

  if (tid < 128) xs[tid] = scalars[((long)t*NN + m0 + tid)*6 + m];

  // ---- load coefficients: Cred[by][j][k=tid] ----
  {
    const float* gp = Cred + (long)by*8192 + tid;
    const float c0v = gp[0];
    c0s[tid] = c0v*(1.f/32.f) + fcb[by*256 + tid];
    u32 cw[16];
    cw[0] = pack2bf(0.f, gp[256]*(1.f/16.f));   // j=0 slot zeroed (in bias)
    #pragma unroll
    for (int j2=1;j2<16;j2++)
      cw[j2] = pack2bf(gp[(2*j2)*256]*(1.f/16.f), gp[(2*j2+1)*256]*(1.f/16.f));
    union { u32 w[4]; uint4 v; } cv4;
    #pragma unroll
    for (int q=0; q<4; q++){
      cv4.w[0]=cw[q*4]; cv4.w[1]=cw[q*4+1]; cv4.w[2]=cw[q*4+2]; cv4.w[3]=cw[q*4+3];
      *(uint4*)&lB[tid*40 + q*8] = cv4.v;    // tid*80B: 16B-aligned
    }
  }
  __syncthreads();

  // A-fragments: lane row = i*16 + l16, k-offset = qd*8
  bf16x8 af[8];
  #pragma unroll
  for (int i=0;i<8;i++){
    const float u = 2.f*xs[i*16 + l16] - 1.f;
    float t0 = 1.f, t1 = u;
    u32 pk[16];
    pk[0] = pack2bf(t0, t1);
    #pragma unroll
    for (int j2=1; j2<16; j2++){
      const float a = 2.f*u*t1 - t0;   // T_{2*j2}
      const float b = 2.f*u*a  - t1;   // T_{2*j2+1}
      pk[j2] = pack2bf(a, b);
      t0 = a; t1 = b;
    }
    u32 w[4];
    #pragma unroll
    for (int c=0;c<4;c++){
      const u32 v01 = (qd & 2) ? pk[8+c]  : pk[c];
      const u32 v23 = (qd & 2) ? pk[12+c] : pk[4+c];
      w[c] = (qd & 1) ? v23 : v01;
    }
    union { u32 u4[4]; bf16x8 v; } cv;
    cv.u4[0]=w[0]; cv.u4[1]=w[1]; cv.u4[2]=w[2]; cv.u4[3]=w[3];
    af[i] = cv.v;
  }

  bf16x8 bfr[4];
  #pragma unroll
  for (int jj=0;jj<4;jj++)
    bfr[jj] = *(const bf16x8*)&lB[(wc0 + jj*16 + l16)*40 + qd*8];

  // hoist the 4 bias values (col depends only on jj)
  float bvj[4];
  #pragma unroll
  for (int jj=0;jj<4;jj++) bvj[jj] = c0s[wc0 + jj*16 + l16];

  u16* st = (u16*)lB;                         // 32 x 264 u16 = 16.5 KB chunk
  u16* zout = zb + ((long)t*NN + m0)*1792 + (m+1)*256;
  #pragma unroll
  for (int c=0;c<4;c++){
    // chunk-local MFMA (rows c*32 .. c*32+31): 32 live accs only
    f32x4 acc2[2][4];
    #pragma unroll
    for (int ii=0;ii<2;ii++)
      #pragma unroll
      for (int jj=0;jj<4;jj++)
        acc2[ii][jj] = __builtin_amdgcn_mfma_f32_16x16x32_bf16(
            af[c*2+ii], bfr[jj], (f32x4){0.f,0.f,0.f,0.f}, 0,0,0);
    u32 pk2[2][4][2];
    #pragma unroll
    for (int ii=0;ii<2;ii++)
      #pragma unroll
      for (int jj=0;jj<4;jj++){
        pk2[ii][jj][0] = pack2bf(gelu_f(acc2[ii][jj][0] + bvj[jj]),
                                 gelu_f(acc2[ii][jj][1] + bvj[jj]));
        pk2[ii][jj][1] = pack2bf(gelu_f(acc2[ii][jj][2] + bvj[jj]),
                                 gelu_f(acc2[ii][jj][3] + bvj[jj]));
      }
    __syncthreads();                          // lB/prev-chunk reads done
    #pragma unroll
    for (int ii=0;ii<2;ii++){
      #pragma unroll
      for (int jj=0;jj<4;jj++){
        const int col = wc0 + jj*16 + l16;
        const int r0 = ii*16 + qd*4;
        st[(r0+0)*264 + col] = (u16)(pk2[ii][jj][0] & 0xffffu);
        st[(r0+1)*264 + col] = (u16)(pk2[ii][jj][0] >> 16);
        st[(r0+2)*264 + col] = (u16)(pk2[ii][jj][1] & 0xffffu);
        st[(r0+3)*264 + col] = (u16)(pk2[ii][jj][1] >> 16);
      }
    }
    __syncthreads();
    #pragma unroll
    for (int it=0; it<4; it++){
      const int f = it*256 + tid;             // 1024 = 32 rows x 32 segs
      const int rowl = f >> 5, seg = f & 31;
      const uint4 v = *(const uint4*)&st[rowl*264 + seg*8];
      *(uint4*)&zout[(long)(c*32 + rowl)*1792 + seg*8] = v;
    }
  }
}

// ---------------- generic bf16-MFMA GEMM (swizzled LDS + async staging) ---------
// EPI: 0 = fp32 +bias; 1 = gelu->bf16; 4 = tanh dot w2 row-sum; 5 = residual mix + LayerNorm
// ASRC: 0 = fp32 A (VGPR cvt path); 1 = bf16 A (async global_load_lds).
// ZQKV: blockIdx.z = {KVlo, KVhi, Q}: z<2 -> contiguous half of the
// interleaved KV record (merged pre-interleaved weights), z=2 -> Q bf16.
// EPI=5 additionally writes a bf16 shadow of the LN output to kvout
// (feeds next layer's ASRC=1 QKV A and the out gemm; f2b == pack2bf RNE,
// so gemm inputs are bit-identical to the old fp32->stage-cvt path).
// launch_bounds(256,2): (256,3+) spills the MFMA accumulators. Do not raise.
template<int BM,int BN,int BK,int WM,int WN,int ASRC,int EPI,int ZQKV>
__global__ void __launch_bounds__(256,2)
gemm_k(const void* __restrict__ Av, const u16* __restrict__ Bt,
       const float* __restrict__ bias, void* Cv,
       int K, int lda, int ldc,
       long strideA, long strideB, long strideBias, long strideC,
       const float* resid, const float* __restrict__ resgate,
       const int* __restrict__ selp, u16* __restrict__ kvout,
       const float* __restrict__ lng, const float* __restrict__ lnb)
{
  static_assert(BK == 64, "swizzle assumes BK=64");
  constexpr int WTM = BM/WM, WTN = BN/WN;
  constexpr int RM = WTM/16, RN = WTN/16;
  __shared__ __align__(16) u16 lA[BM*64];
  __shared__ __align__(16) u16 lB[BN*64];

  const int tid = threadIdx.x;
  const int by  = blockIdx.y;
  const int m0  = blockIdx.x * BM;
  const int lane = tid & 63, wvi = tid >> 6;
  const int wr = wvi / WN, wc = wvi % WN;
  const int wr0 = wr * WTM, wc0 = wc * WTN;
  const int l16 = lane & 15, qd = lane >> 4;
  // per-lane source-column permutation implementing the XOR swizzle (see gl_lds16)
  const int csrc = (((lane & 7) ^ (lane >> 3)) << 3);

  int zq = 0;
  if constexpr (ZQKV) zq = blockIdx.z;

  long aoff = (long)by * strideA;
  if (selp) aoff += (long)selp[0] * strideA;
  const float* A32 = (const float*)Av;
  const u16*   A16 = (const u16*)Av;
  const u16*   Bp  = Bt + (long)by * strideB + (long)zq * 65536;

  f32x4 acc[RM][RN];
  #pragma unroll
  for(int i=0;i<RM;i++)
    #pragma unroll
    for(int j=0;j<RN;j++) acc[i][j] = (f32x4){0.f,0.f,0.f,0.f};

  for(int k0=0;k0<K;k0+=BK){
    if constexpr (ASRC == 0){
      for(int idx=tid; idx < BM*16; idx += 256){
        int r = idx >> 4, c = (idx & 15)*4;
        const float4 v = *(const float4*)(A32 + aoff + (long)(m0+r)*lda + k0 + c);
        uint2 o2; o2.x = pack2bf(v.x, v.y); o2.y = pack2bf(v.z, v.w);
        *(uint2*)&lA[swz64(r, c)] = o2;
      }
    } else {
      #pragma unroll
      for(int ch = wvi; ch < BM/8; ch += 4){
        const int r = ch*8 + (lane>>3);
        gl_lds16(A16 + aoff + (long)(m0+r)*lda + k0 + csrc, &lA[ch*512]);
      }
    }
    #pragma unroll
    for(int ch = wvi; ch < BN/8; ch += 4){
      const int n = ch*8 + (lane>>3);
      gl_lds16(Bp + (long)n*K + k0 + csrc, &lB[ch*512]);
    }
    __syncthreads();
    #pragma unroll
    for(int ks=0; ks<BK; ks+=32){
      bf16x8 af[RM], bfr[RN];
      #pragma unroll
      for(int i=0;i<RM;i++) af[i]  = *(const bf16x8*)&lA[swz64(wr0 + i*16 + l16, ks + qd*8)];
      #pragma unroll
      for(int j=0;j<RN;j++) bfr[j] = *(const bf16x8*)&lB[swz64(wc0 + j*16 + l16, ks + qd*8)];
      #pragma unroll
      for(int i=0;i<RM;i++)
        #pragma unroll
        for(int j=0;j<RN;j++)
          acc[i][j] = __builtin_amdgcn_mfma_f32_16x16x32_bf16(af[i], bfr[j], acc[i][j], 0,0,0);
    }
    __syncthreads();
  }

  if constexpr (EPI == 4){
    float* rsum = (float*)lA;   // alias dead A-tile (post-barrier safe)
    #pragma unroll
    for(int i=0;i<RM;i++){
      #pragma unroll
      for(int r=0;r<4;r++){
        float part = 0.f;
        #pragma unroll
        for(int jj=0;jj<RN;jj++){
          const int col = wc0 + jj*16 + l16;
          const float v = fast_tanh(acc[i][jj][r] + bias[col]);
          part += v * resid[col];
        }
        part += __shfl_xor(part,1); part += __shfl_xor(part,2);
        part += __shfl_xor(part,4); part += __shfl_xor(part,8);
        if (l16 == 0) rsum[wc*BM + wr0 + i*16 + qd*4 + r] = part;
      }
    }
    __syncthreads();
    if (tid < BM){
      float s = 0.f;
      #pragma unroll
      for(int w=0;w<WN;w++) s += rsum[w*BM + tid];
      ((float*)Cv)[m0 + tid] = s;
    }
    return;
  } else if constexpr (EPI == 5){
    // residual mix -> LayerNorm fused; Cv == resid buffer (in-place per-row)
    float* red1 = (float*)lA;            // WN*BM
    float* red2 = red1 + WN*BM;          // WN*BM
    float* muv  = red2 + WN*BM;          // BM*2
    const float alpha = 1.f/(1.f + __expf(-resgate[by]));
    #pragma unroll
    for(int i=0;i<RM;i++){
      #pragma unroll
      for(int r=0;r<4;r++){
        const int rloc = wr0 + i*16 + qd*4 + r;
        const int row = m0 + rloc;
        float s1 = 0.f, s2 = 0.f;
        #pragma unroll
        for(int j=0;j<RN;j++){
          const int col = wc0 + j*16 + l16;
          float v = acc[i][j][r] + bias[(long)by*strideBias + col];
          const float hv = resid[(long)by*strideC + (long)row*ldc + col];
          v = v*alpha + hv*(1.f - alpha);
          acc[i][j][r] = v;
          s1 += v; s2 += v*v;
        }
        s1 += __shfl_xor(s1,1); s1 += __shfl_xor(s1,2); s1 += __shfl_xor(s1,4); s1 += __shfl_xor(s1,8);
        s2 += __shfl_xor(s2,1); s2 += __shfl_xor(s2,2); s2 += __shfl_xor(s2,4); s2 += __shfl_xor(s2,8);
        if (l16 == 0){ red1[wc*BM + rloc] = s1; red2[wc*BM + rloc] = s2; }
      }
    }
    __syncthreads();
    if (tid < BM){
      float s1 = 0.f, s2 = 0.f;
      #pragma unroll
      for(int w=0;w<WN;w++){ s1 += red1[w*BM + tid]; s2 += red2[w*BM + tid]; }
      const float mu = s1*(1.f/256.f);
      const float var = s2*(1.f/256.f) - mu*mu;
      muv[tid*2]   = mu;
      muv[tid*2+1] = rsqrtf(fmaxf(var, 0.f) + 1e-5f);
    }
    __syncthreads();
    #pragma unroll
    for(int i=0;i<RM;i++){
      #pragma unroll
      for(int r=0;r<4;r++){
        const int rloc = wr0 + i*16 + qd*4 + r;
        const int row = m0 + rloc;
        const float mu = muv[rloc*2], rs = muv[rloc*2+1];
        #pragma unroll
        for(int j=0;j<RN;j++){
          const int col = wc0 + j*16 + l16;
          const float o = (acc[i][j][r]-mu)*rs*lng[by*256+col] + lnb[by*256+col];
          const long cidx = (long)by*strideC + (long)row*ldc + col;
          ((float*)Cv)[cidx] = o;
          kvout[cidx] = f2b(o);               // bf16 shadow for ASRC=1 readers
        }
      }
    }
    return;
  } else {
    #pragma unroll
    for(int i=0;i<RM;i++){
      #pragma unroll
      for(int j=0;j<RN;j++){
        const int col = wc0 + j*16 + l16;
        float bv;
        if constexpr (ZQKV)
          bv = bias[(zq==2) ? (1024 + (long)by*256 + col) : ((long)by*512 + zq*256 + col)];
        else
          bv = bias[(long)by*strideBias + col];
        #pragma unroll
        for(int r=0;r<4;r++){
          const int row = m0 + wr0 + i*16 + qd*4 + r;
          float v = acc[i][j][r] + bv;
          if constexpr (ZQKV){
            if (zq == 2)
              ((u16*)Cv)[(long)by*strideC + (long)row*ldc + col] = f2b(v);   // Q bf16
            else
              // contiguous half of the interleaved KV record (32B-dense)
              kvout[((long)by*NN + row)*512 + zq*256 + col] = f2b(v);
          } else {
            const long cidx = (long)by*strideC + (long)row*ldc + col;
            if constexpr (EPI == 0) ((float*)Cv)[cidx] = v;
            else ((u16*)Cv)[cidx] = f2b(gelu_f(v));
          }
        }
      }
    }
  }
}

// ---------------- IMA combine ----------------
__global__ void ima_combine(const u16* __restrict__ zb, const float* __restrict__ wbuf,
                            float* __restrict__ H, u16* __restrict__ H16){
  const int row = blockIdx.x*4 + (threadIdx.x>>6);
  const int lane = threadIdx.x & 63;
  const float* w7 = wbuf + (long)row*7;
  float w[7]; float mx = -1e30f;
  #pragma unroll
  for(int m=0;m<7;m++){ w[m] = w7[m]; mx = fmaxf(mx, w[m]); }
  float sum = 0.f;
  #pragma unroll
  for(int m=0;m<7;m++){ w[m] = __expf(w[m]-mx); sum += w[m]; }
  const float inv = __builtin_amdgcn_rcpf(sum);
  float4 acc = {0,0,0,0};
  #pragma unroll
  for(int m=0;m<7;m++){
    const u16x4 z4 = *(const u16x4*)&zb[((long)row*7 + m)*256 + lane*4];
    const float p = w[m]*inv;
    acc.x += p*b2f(z4.x); acc.y += p*b2f(z4.y); acc.z += p*b2f(z4.z); acc.w += p*b2f(z4.w);
  }
  *(float4*)&H[(long)row*256 + lane*4] = acc;
  uint2 o; o.x = pack2bf(acc.x, acc.y); o.y = pack2bf(acc.z, acc.w);
  *(uint2*)&H16[(long)row*256 + lane*4] = o;   // bf16 shadow for ASRC=1 QKV
}

// ---------------- attention aggregation: interleaved-KV gather ----------------
// KV record = 64 chunks of 16B; chunk l = {K[4l..4l+3], V[4l..4l+3]}.
// Lane l owns 4 K dims AND 4 V dims of head (l>>3); 8 lanes per head.
// R12: 128-thread blocks, 2 dests each. R2-form inner math (verified 66.2us).
// 4-dest/256-thread showed 42% occupancy (block residency held by slowest
// dest, E[max4 of Poisson16]~21); 1-dest/64-thread hit the 16-wg/CU cap
// (R5). 2-dest/128-thread: 16wg x 2 waves = 32 waves/CU (no cap), E[max2]~18.
__global__ void __launch_bounds__(128)
attn_agg(const u16* __restrict__ Q16, const u16* __restrict__ KV,
         u16* __restrict__ AGG,
         const int* __restrict__ offs, const int* __restrict__ elist,
         const float* __restrict__ canon){
  const int e = blockIdx.y, dt = 1 - e;
  const int d = blockIdx.x*2 + (threadIdx.x>>6);
  const int lane = threadIdx.x & 63;
  const float scale = canon[e*8 + (lane>>3)] * 0.17677669529663687f;

  // Q dims lane*4..+3 (8B per lane, 512B per dest row)
  const uint2 qv = *(const uint2*)&Q16[((long)dt*NN + d)*256 + lane*4];
  const float q0 = b2f((u16)(qv.x&0xffff)), q1 = b2f((u16)(qv.x>>16));
  const float q2 = b2f((u16)(qv.y&0xffff)), q3 = b2f((u16)(qv.y>>16));

  const int p0 = offs[e*(NN+1) + d], p1 = offs[e*(NN+1) + d + 1];
  const int* el = elist + (long)e*EE;
  const u16* KVb = KV + (long)e*NN*512;

  float a0=0.f, a1=0.f, a2=0.f, a3=0.f;
  float den = 0.f;

  auto process = [&](const uint4 kv){
    float dp = q0*b2f((u16)(kv.x&0xffff)) + q1*b2f((u16)(kv.x>>16))
             + q2*b2f((u16)(kv.y&0xffff)) + q3*b2f((u16)(kv.y>>16));
    dp += __shfl_xor(dp,1); dp += __shfl_xor(dp,2); dp += __shfl_xor(dp,4);
    const float w = __expf(dp*scale);   // identical across the 8-lane head group
    den += w;
    a0 = fmaf(w, b2f((u16)(kv.z&0xffff)), a0);
    a1 = fmaf(w, b2f((u16)(kv.z>>16)),    a1);
    a2 = fmaf(w, b2f((u16)(kv.w&0xffff)), a2);
    a3 = fmaf(w, b2f((u16)(kv.w>>16)),    a3);
  };

  int p = p0;
  for(; p+8 <= p1; p += 8){
    uint4 kv[8];
    #pragma unroll
    for(int u=0;u<8;u++) kv[u] = *(const uint4*)&KVb[(long)el[p+u]*512 + lane*8];
    #pragma unroll
    for(int u=0;u<8;u++) process(kv[u]);
  }
  for(; p+2 <= p1; p += 2){
    const uint4 a = *(const uint4*)&KVb[(long)el[p]*512 + lane*8];
    const uint4 b = *(const uint4*)&KVb[(long)el[p+1]*512 + lane*8];
    process(a); process(b);
  }
  if (p < p1){
    const uint4 a = *(const uint4*)&KVb[(long)el[p]*512 + lane*8];
    process(a);
  }

  uint2 o = {0,0};
  if (p1 > p0){
    const float r = 1.f/den;
    o.x = pack2bf(a0*r, a1*r);
    o.y = pack2bf(a2*r, a3*r);
  }
  *(uint2*)&AGG[((long)dt*NN + d)*256 + lane*4] = o;
}

// ---------------- host ----------------
extern "C" void kernel_launch(void* const* d_in, const int* in_sizes, int n_in,
                              void* d_out, int out_size, void* d_ws, size_t ws_size,
                              hipStream_t stream) {
  const float* node_ft = (const float*)d_in[0];
  const float* scalars = (const float*)d_in[1];
  const int*   src_idx = (const int*)d_in[2];
  const int*   dst_idx = (const int*)d_in[3];
  const float* proj_w  = (const float*)d_in[4];
  const float* proj_b  = (const float*)d_in[5];
  const float* pv_ww   = (const float*)d_in[6];
  const float* pv_wb   = (const float*)d_in[7];
  const float* pv_lw   = (const float*)d_in[8];
  const float* pv_lb   = (const float*)d_in[9];
  const float* pv_sw   = (const float*)d_in[10];
  const float* pv_sb   = (const float*)d_in[11];
  const float* pv_gw   = (const float*)d_in[12];
  const float* pv_gb   = (const float*)d_in[13];
  const float* pv_fcw  = (const float*)d_in[14];
  const float* pv_fcb  = (const float*)d_in[15];
  const float* ima_w1  = (const float*)d_in[16];
  const float* ima_b1  = (const float*)d_in[17];
  const float* ima_w2  = (const float*)d_in[18];
  const float* lyr_k_w = (const float*)d_in[19];
  const float* lyr_q_w = (const float*)d_in[20];
  const float* lyr_v_w = (const float*)d_in[21];
  const float* lyr_fc_w= (const float*)d_in[22];
  const float* lyr_k_b = (const float*)d_in[23];
  const float* lyr_q_b = (const float*)d_in[24];
  const float* lyr_v_b = (const float*)d_in[25];
  const float* lyr_fc_b= (const float*)d_in[26];
  const float* lyr_att_w=(const float*)d_in[27];
  const float* lyr_val_w=(const float*)d_in[28];
  const float* lyr_canon=(const float*)d_in[29];
  const float* lyr_res = (const float*)d_in[30];
  const float* lyr_ln_g= (const float*)d_in[31];
  const float* lyr_ln_b= (const float*)d_in[32];
  const float* out_w   = (const float*)d_in[33];
  const float* out_b   = (const float*)d_in[34];
  const int*   sel     = (const int*)d_in[35];
  float* outp = (float*)d_out;

  char* ws = (char*)d_ws;
  size_t o = 0;
  auto alloc = [&](size_t bytes)->char*{ char* p = ws + o; o = (o + bytes + 255) & ~(size_t)255; return p; };

  int*   cnt    = (int*)  alloc(2*NN*4);
  int*   cur    = (int*)  alloc(2*NN*4);
  int*   offs   = (int*)  alloc(2*(NN+1)*4);
  int*   elist  = (int*)  alloc(2*EE*4);
  u16*   projwt = (u16*)  alloc((size_t)TT*128*256*2);
  u16*   imaw1t = (u16*)  alloc((size_t)256*128*2);
  u16*   qkvwt  = (u16*)  alloc((size_t)4*196608*2);   // per (l,t): [mergedKV 512x256 | Q 256x256]
  u16*   fcwt   = (u16*)  alloc((size_t)4*256*256*2);
  u16*   outwt  = (u16*)  alloc((size_t)64*256*2);
  float* hbuf   = (float*)alloc((size_t)TT*NN*256*4);
  u16*   hbuf16 = (u16*)  alloc((size_t)TT*NN*256*2);     // bf16 shadow of h
  float* wbuf   = (float*)alloc((size_t)TT*NN*7*4);
  float* Cred   = (float*)alloc((size_t)12*32*256*4);     // cheb coefficients (fp32)
  float* qkvb   = (float*)alloc((size_t)TT*3*2*256*4);    // per l: [t0 m512|t1 m512|t0 Q256|t1 Q256]
  char*  arena  = alloc((size_t)176160768);
  if (o > ws_size) return;

  u16*   zbuf  = (u16*)arena;                         // (T,N,7,256) bf16, phase A
  u16*   Qb16  = (u16*)arena;                         // phase B (zbuf dead after ima_combine)
  u16*   KVb   = (u16*)(arena + 16777216);            // (T,N,512) bf16 interleaved K|V
  u16*   AGG16 = (u16*)(arena + 50331648);            // (T,N,256) bf16

  // ---- CSR build ----
  hipMemsetAsync(cnt, 0, 2*NN*4, stream);
  hipMemsetAsync(cur, 0, 2*NN*4, stream);
  hipMemsetAsync(Cred, 0, (size_t)12*32*256*4, stream);
  csr_hist   <<<2*EE/256, 256, 0, stream>>>(dst_idx, cnt);
  csr_scan   <<<2, 256, 0, stream>>>(cnt, offs);
  csr_scatter<<<2*EE/256, 256, 0, stream>>>(dst_idx, src_idx, offs, cur, elist);

  // ---- weights prep ----
  tconv<<<dim3( 4,8, 2), dim3(32,8), 0, stream>>>(proj_w,   projwt, 128, 256, 32768L);
  tconv<<<dim3( 8,4, 1), dim3(32,8), 0, stream>>>(ima_w1,   imaw1t, 256, 128, 32768L);
  tconv<<<dim3( 8,8, 4), dim3(32,8), 0, stream>>>(lyr_q_w,  qkvwt + 131072, 256, 256, 196608L);
  tconv<<<dim3( 8,8, 4), dim3(32,8), 0, stream>>>(lyr_fc_w, fcwt,   256, 256, 65536L);
  tconv<<<dim3( 8,2, 1), dim3(32,8), 0, stream>>>(out_w,    outwt,  256, 64, 16384L);
  eff_w<<<dim3(8,4,2), 256, 0, stream>>>(lyr_k_w, lyr_v_w, lyr_k_b, lyr_v_b,
                                         lyr_att_w, lyr_val_w, qkvwt, qkvb);
  pack_qb<<<4, 256, 0, stream>>>(lyr_q_b, qkvb);

  // ---- Chebyshev fit of posvect (per-h DCT inside cheb_g) ----
  cheb_g<<<dim3(8,12,4), 256, 0, stream>>>(pv_ww, pv_wb, pv_lw, pv_lb,
                                           pv_sw, pv_sb, pv_gw, pv_gb, pv_fcw, Cred);

  // ---- h0 = gelu(node_ft @ proj_w + b) -> zbuf slot 0 ----
  gemm_k<64,256,64,1,4,0,1,0><<<dim3(256,TT), 256, 0, stream>>>(
      node_ft, projwt, proj_b, zbuf, 128, 128, 1792,
      (long)NN*128, 32768L, 256L, (long)NN*1792, nullptr, nullptr, nullptr, nullptr,
      nullptr, nullptr);

  // ---- posvect -> zbuf slots 1..6 (Chebyshev evaluation, K=32) ----
  posvect2<<<dim3(128,12), 256, 0, stream>>>(scalars, Cred, pv_fcb, zbuf);

  // ---- IMA gate fused epilogue, then softmax-combine (fp32 + bf16 shadow) ----
  gemm_k<64,128,64,2,2,1,4,0><<<dim3(3584,1), 256, 0, stream>>>(
      zbuf, imaw1t, ima_b1, wbuf, 256, 256, 0,
      0L, 0L, 0L, 0L, ima_w2, nullptr, nullptr, nullptr, nullptr, nullptr);
  ima_combine<<<TT*NN/4, 256, 0, stream>>>(zbuf, wbuf, hbuf, hbuf16);

  // ---- layers ----
  for (int l = 0; l < 2; ++l){
    // merged K/Q/V from bf16 h (ASRC=1): z=0/1 -> KV record halves, z=2 -> Q
    gemm_k<64,256,64,1,4,1,0,1><<<dim3(256,TT,3), 256, 0, stream>>>(
        hbuf16, qkvwt + (size_t)l*393216, qkvb + (size_t)l*1536, Qb16, 256, 256, 256,
        (long)NN*256, 196608L, 0L, (long)NN*256, nullptr, nullptr, nullptr, KVb,
        nullptr, nullptr);

    attn_agg<<<dim3(NN/2, 2), 128, 0, stream>>>(Qb16, KVb, AGG16, offs, elist,
                                                lyr_canon + l*2*8);

    // fc + residual mix + LayerNorm fused, in-place on hbuf (+ bf16 shadow)
    gemm_k<64,256,64,1,4,1,5,0><<<dim3(256,TT), 256, 0, stream>>>(
        AGG16, fcwt + (size_t)l*2*65536, lyr_fc_b + l*2*256, hbuf, 256, 256, 256,
        (long)NN*256, 65536L, 256L, (long)NN*256, hbuf, lyr_res + l*2, nullptr, hbuf16,
        lyr_ln_g + l*2*256, lyr_ln_b + l*2*256);
  }

  // ---- out = h[sel] @ out_w + out_b (bf16 A, ASRC=1) ----
  gemm_k<256,64,64,4,1,1,0,0><<<dim3(64,1), 256, 0, stream>>>(
      hbuf16, outwt, out_b, outp, 256, 256, 64,
      (long)NN*256, 0L, 0L, 0L, nullptr, nullptr, sel, nullptr, nullptr, nullptr);

  (void)in_sizes; (void)n_in; (void)out_size;
}